// Round 1
// baseline (1706.285 us; speedup 1.0000x reference)
//
#include <hip/hip_runtime.h>
#include <hip/hip_bf16.h>

#define N_TOK 2048
#define HIDDEN 5120
#define HEAD_DIM 128
#define HQ 40
#define HKV 8
#define QKV_OUT 7208
#define Q_SIZE 5120
#define KV_SIZE 1024

typedef __attribute__((ext_vector_type(8))) short bf16x8;
typedef __attribute__((ext_vector_type(4))) float f32x4;
typedef __attribute__((ext_vector_type(4))) unsigned short us4;

__device__ inline unsigned short f2bf(float f) {
    return __builtin_bit_cast(unsigned short, __float2bfloat16(f));
}
__device__ inline float bf2f(unsigned short s) {
    unsigned u = ((unsigned)s) << 16;
    return __builtin_bit_cast(float, u);
}
__device__ inline f32x4 mfma16(bf16x8 a, bf16x8 b, f32x4 c) {
    return __builtin_amdgcn_mfma_f32_16x16x32_bf16(a, b, c, 0, 0, 0);
}

// ---------------- sort tokens by modality (stable) ----------------
__global__ void k_sort(const int* __restrict__ mids_raw, int* __restrict__ meta,
                       int* __restrict__ perm) {
    int l = threadIdx.x;  // 64 threads, 1 wave
    // detect int64 vs int32: if int64, all odd 32-bit words (high words) are 0
    int oddnz = 0;
    for (int c = 0; c < 32; ++c) {
        int idx = c * 64 + l;
        int v = mids_raw[idx];
        if ((idx & 1) && v != 0) oddnz = 1;
    }
    bool is64 = (__ballot(oddnz) == 0ULL);
    int c0 = 0, c1 = 0;
    for (int c = 0; c < 32; ++c) {
        int i = c * 64 + l;
        int m = is64 ? mids_raw[2 * i] : mids_raw[i];
        c0 += (m == 0); c1 += (m == 1);
    }
    for (int o = 32; o; o >>= 1) { c0 += __shfl_xor(c0, o); c1 += __shfl_xor(c1, o); }
    if (l == 0) { meta[0] = 0; meta[1] = c0; meta[2] = c0 + c1; meta[3] = N_TOK; }
    int r0 = 0, r1 = c0, r2 = c0 + c1;
    unsigned long long below = (1ULL << l) - 1ULL;
    for (int c = 0; c < 32; ++c) {
        int i = c * 64 + l;
        int m = is64 ? mids_raw[2 * i] : mids_raw[i];
        unsigned long long b0 = __ballot(m == 0), b1 = __ballot(m == 1), b2 = __ballot(m == 2);
        int pos = (m == 0) ? r0 + __popcll(b0 & below)
                : (m == 1) ? r1 + __popcll(b1 & below)
                           : r2 + __popcll(b2 & below);
        perm[pos] = i;
        r0 += __popcll(b0); r1 += __popcll(b1); r2 += __popcll(b2);
    }
}

// ---------------- pre-norm: h_sorted = rmsnorm(hidden[perm]) * (w+1), bf16 ----------------
__global__ __launch_bounds__(256) void k_prenorm(const float* __restrict__ hidden,
        const float* __restrict__ pnw, const int* __restrict__ meta,
        const int* __restrict__ perm, unsigned short* __restrict__ h) {
    int i = blockIdx.x;
    int m = (i >= meta[1]) + (i >= meta[2]);
    int t = perm[i];
    const float4* x = (const float4*)(hidden + (size_t)t * HIDDEN);
    const float4* wv = (const float4*)(pnw + (size_t)m * HIDDEN);
    int tid = threadIdx.x;
    float4 xv[5];
    float ss = 0.f;
#pragma unroll
    for (int j = 0; j < 5; ++j) {
        xv[j] = x[tid + j * 256];
        ss += xv[j].x * xv[j].x + xv[j].y * xv[j].y + xv[j].z * xv[j].z + xv[j].w * xv[j].w;
    }
    for (int o = 32; o; o >>= 1) ss += __shfl_xor(ss, o);
    __shared__ float red[4];
    if ((tid & 63) == 0) red[tid >> 6] = ss;
    __syncthreads();
    float rms = rsqrtf((red[0] + red[1] + red[2] + red[3]) * (1.f / HIDDEN) + 1e-6f);
    us4* dst = (us4*)(h + (size_t)i * HIDDEN);
#pragma unroll
    for (int j = 0; j < 5; ++j) {
        float4 w = wv[tid + j * 256];
        us4 o4;
        o4.x = f2bf(xv[j].x * rms * (w.x + 1.f));
        o4.y = f2bf(xv[j].y * rms * (w.y + 1.f));
        o4.z = f2bf(xv[j].z * rms * (w.z + 1.f));
        o4.w = f2bf(xv[j].w * rms * (w.w + 1.f));
        dst[tid + j * 256] = o4;
    }
}

// ---------------- MoE GEMM: C[i,j] = sum_k A[i,k] * B[m, j, k] ----------------
// A bf16 sorted rows, B fp32. 128x128 tile, BK=64, 4 waves of 64x64.
template <int NOUT, bool SCATTER>
__global__ __launch_bounds__(256) void k_moe_gemm(
        const unsigned short* __restrict__ A, const float* __restrict__ B,
        unsigned short* __restrict__ outB, float* __restrict__ outF,
        const int* __restrict__ meta, const int* __restrict__ perm) {
    int mz = blockIdx.z;
    int rowS = meta[mz], rowE = meta[mz + 1];
    int row0 = rowS + blockIdx.y * 128;
    if (row0 >= rowE) return;
    int col0 = blockIdx.x * 128;
    const float* Bm = B + (size_t)mz * NOUT * HIDDEN;

    __shared__ __align__(16) unsigned short As[128 * 64];
    __shared__ __align__(16) unsigned short Bs[128 * 64];
    int tid = threadIdx.x, l = tid & 63, w = tid >> 6;
    int wr = (w >> 1) * 64, wc = (w & 1) * 64;

    f32x4 acc[4][4] = {};
    int sr = tid >> 1, half = tid & 1;
    int arow = row0 + sr;
    if (arow > N_TOK - 1) arow = N_TOK - 1;
    const unsigned short* aptr = A + (size_t)arow * HIDDEN + half * 32;
    int bcol = col0 + sr;
    bool bok = (bcol < NOUT);
    const float* bptr = Bm + (size_t)(bok ? bcol : 0) * HIDDEN + half * 32;

    char* awp[4]; char* bwp[4];
#pragma unroll
    for (int q = 0; q < 4; ++q) {
        int boff = sr * 128 + ((((half * 4 + q) * 16)) ^ ((sr & 7) << 4));
        awp[q] = (char*)As + boff;
        bwp[q] = (char*)Bs + boff;
    }

#pragma unroll 1
    for (int kk = 0; kk < HIDDEN; kk += 64) {
        bf16x8 av[4];
#pragma unroll
        for (int q = 0; q < 4; ++q) av[q] = *(const bf16x8*)(aptr + kk + q * 8);
        bf16x8 bw[4];
#pragma unroll
        for (int q = 0; q < 4; ++q) {
            float4 u, v;
            if (bok) {
                u = ((const float4*)(bptr + kk))[2 * q];
                v = ((const float4*)(bptr + kk))[2 * q + 1];
            } else {
                u = make_float4(0.f, 0.f, 0.f, 0.f);
                v = u;
            }
            bf16x8 pk;
            pk[0] = (short)f2bf(u.x); pk[1] = (short)f2bf(u.y);
            pk[2] = (short)f2bf(u.z); pk[3] = (short)f2bf(u.w);
            pk[4] = (short)f2bf(v.x); pk[5] = (short)f2bf(v.y);
            pk[6] = (short)f2bf(v.z); pk[7] = (short)f2bf(v.w);
            bw[q] = pk;
        }
        __syncthreads();  // all waves done reading previous tile
#pragma unroll
        for (int q = 0; q < 4; ++q) {
            *(bf16x8*)awp[q] = av[q];
            *(bf16x8*)bwp[q] = bw[q];
        }
        __syncthreads();
#pragma unroll
        for (int ks = 0; ks < 2; ++ks) {
            bf16x8 af[4], bfm[4];
#pragma unroll
            for (int mi = 0; mi < 4; ++mi) {
                int row = wr + mi * 16 + (l & 15);
                af[mi] = *(const bf16x8*)((char*)As + row * 128 +
                            ((ks * 64 + (l >> 4) * 16) ^ ((row & 7) << 4)));
            }
#pragma unroll
            for (int ni = 0; ni < 4; ++ni) {
                int row = wc + ni * 16 + (l & 15);
                bfm[ni] = *(const bf16x8*)((char*)Bs + row * 128 +
                            ((ks * 64 + (l >> 4) * 16) ^ ((row & 7) << 4)));
            }
#pragma unroll
            for (int mi = 0; mi < 4; ++mi)
#pragma unroll
                for (int ni = 0; ni < 4; ++ni)
                    acc[mi][ni] = mfma16(af[mi], bfm[ni], acc[mi][ni]);
        }
    }
    // epilogue: C/D layout col=lane&15, row=(lane>>4)*4+r
#pragma unroll
    for (int mi = 0; mi < 4; ++mi) {
        int rbase = row0 + wr + mi * 16 + ((l >> 4) << 2);
#pragma unroll
        for (int ni = 0; ni < 4; ++ni) {
            int col = col0 + wc + ni * 16 + (l & 15);
            if (col >= NOUT) continue;
#pragma unroll
            for (int r = 0; r < 4; ++r) {
                int row = rbase + r;
                if (row >= rowE) continue;
                if (SCATTER) {
                    int t = perm[row];
                    outF[(size_t)t * HIDDEN + col] = acc[mi][ni][r];
                } else {
                    outB[(size_t)row * NOUT + col] = f2bf(acc[mi][ni][r]);
                }
            }
        }
    }
}

// ---------------- qk-norm + rope + gate ----------------
__global__ __launch_bounds__(256) void k_qknorm(const unsigned short* __restrict__ qkv,
        const float* __restrict__ rope, const float* __restrict__ qnw,
        const float* __restrict__ knw, const int* __restrict__ meta,
        const int* __restrict__ perm, unsigned short* __restrict__ qb,
        unsigned short* __restrict__ kb, float* __restrict__ gate) {
    int i = blockIdx.x;
    int m = (i >= meta[1]) + (i >= meta[2]);
    int t = perm[i];
    int tid = threadIdx.x, w = tid >> 6, l = tid & 63;
    const unsigned short* base = qkv + (size_t)i * QKV_OUT;
    const float* rp = rope + (size_t)t * HEAD_DIM;
    const float qscale = 0.08838834764831845f;  // 1/sqrt(128)
    for (int hh = w; hh < 48; hh += 4) {
        bool isq = hh < 40;
        const unsigned short* src = base + (isq ? hh * 128 : Q_SIZE + (hh - 40) * 128);
        float x0 = bf2f(src[2 * l]), x1 = bf2f(src[2 * l + 1]);
        float ss = x0 * x0 + x1 * x1;
        for (int o = 32; o; o >>= 1) ss += __shfl_xor(ss, o);
        float rms = rsqrtf(ss * (1.f / 128.f) + 1e-6f);
        const float* nw = (isq ? qnw : knw) + m * 128;
        float y0 = x0 * rms * (nw[2 * l] + 1.f);
        float y1 = x1 * rms * (nw[2 * l + 1] + 1.f);
        float p0 = __shfl_xor(y0, 32);
        float p1 = __shfl_xor(y1, 32);
        float r0v, r1v;
        if (l < 32) {       // d = 2l, 2l+1 in [0,64): out = x1*cos - x2*sin
            int d = 2 * l;
            r0v = y0 * rp[64 + d] - p0 * rp[d];
            r1v = y1 * rp[64 + d + 1] - p1 * rp[d + 1];
        } else {            // d in [64,128): out = x1*sin + x2*cos at d' = d-64
            int d = 2 * l - 64;
            r0v = p0 * rp[d] + y0 * rp[64 + d];
            r1v = p1 * rp[d + 1] + y1 * rp[64 + d + 1];
        }
        if (isq) {
            r0v *= qscale; r1v *= qscale;
            unsigned short* dst = qb + (size_t)i * Q_SIZE + hh * 128 + 2 * l;
            dst[0] = f2bf(r0v); dst[1] = f2bf(r1v);
        } else {
            unsigned short* dst = kb + (size_t)i * KV_SIZE + (hh - 40) * 128 + 2 * l;
            dst[0] = f2bf(r0v); dst[1] = f2bf(r1v);
        }
    }
    if (tid < HQ) {
        float g = bf2f(base[Q_SIZE + 2 * KV_SIZE + tid]);
        gate[(size_t)i * HQ + tid] = 1.f / (1.f + expf(-g));
    }
}

// ---------------- transpose V: [tok][kvh][128] -> [kvh][128][tok] ----------------
__global__ __launch_bounds__(256) void k_vtrans(const unsigned short* __restrict__ qkv,
                                                unsigned short* __restrict__ vT) {
    int t0 = blockIdx.x * 64, db = blockIdx.y * 64, kvh = blockIdx.z;
    __shared__ unsigned short tile[64][68];
    int tid = threadIdx.x;
    int tr = tid >> 2, seg = tid & 3;
    const unsigned short* src = qkv + (size_t)(t0 + tr) * QKV_OUT + Q_SIZE + KV_SIZE +
                                kvh * 128 + db + seg * 16;
    us4* drow = (us4*)&tile[tr][seg * 16];
#pragma unroll
    for (int q = 0; q < 4; ++q) drow[q] = ((const us4*)src)[q];
    __syncthreads();
    int dr = tid >> 2;
    unsigned short* dst = vT + ((size_t)kvh * 128 + db + dr) * N_TOK + t0 + seg * 16;
    unsigned short buf[16];
#pragma unroll
    for (int j = 0; j < 16; ++j) buf[j] = tile[seg * 16 + j][dr];
#pragma unroll
    for (int q = 0; q < 4; ++q) ((us4*)dst)[q] = ((us4*)buf)[q];
}

// ---------------- flash attention (non-causal, GQA 5:1) ----------------
__global__ __launch_bounds__(256) void k_attn(
        const unsigned short* __restrict__ qb,   // [2048][5120] bf16, pre-scaled
        const unsigned short* __restrict__ kb,   // [2048][1024] bf16
        const unsigned short* __restrict__ vT,   // [8][128][2048] bf16
        const float* __restrict__ gate,          // [2048][40] fp32 sigmoid
        unsigned short* __restrict__ og) {       // [2048][5120] bf16
    int qt = blockIdx.x, qh = blockIdx.y, kvh = qh / 5;
    int tid = threadIdx.x, w = tid >> 6, l = tid & 63;
    int q0 = qt * 128 + w * 32;
    __shared__ __align__(16) char smem[49152];
    char* Ks = smem;                       // [64 rows][256B] swizzled
    char* Vs = smem + 16384;               // [128 rows][128B] swizzled (V^T tile)
    char* Ps = smem + 32768 + w * 4096;    // per-wave [32 rows][128B]

    bf16x8 qf[2][4];
#pragma unroll
    for (int mi = 0; mi < 2; ++mi)
#pragma unroll
        for (int ks = 0; ks < 4; ++ks)
            qf[mi][ks] = *(const bf16x8*)(qb + (size_t)(q0 + mi * 16 + (l & 15)) * Q_SIZE +
                                          qh * 128 + ks * 32 + (l >> 4) * 8);

    f32x4 oacc[2][8] = {};
    float mrun[2][4], lrun[2][4];
#pragma unroll
    for (int mi = 0; mi < 2; ++mi)
#pragma unroll
        for (int r = 0; r < 4; ++r) { mrun[mi][r] = -__builtin_inff(); lrun[mi][r] = 0.f; }

    int kr = tid >> 2, kseg = tid & 3;   // K staging: row 0..63, 32 bf16 each
    int vr = tid >> 1, vh2 = tid & 1;    // V staging: row 0..127, 32 bf16 each

#pragma unroll 1
    for (int kt = 0; kt < 32; ++kt) {
        int t0 = kt * 64;
        bf16x8 kv4[4], vv4[4];
        const unsigned short* ksrc = kb + (size_t)(t0 + kr) * KV_SIZE + kvh * 128 + kseg * 32;
        const unsigned short* vsrc = vT + ((size_t)kvh * 128 + vr) * N_TOK + t0 + vh2 * 32;
#pragma unroll
        for (int q = 0; q < 4; ++q) {
            kv4[q] = *(const bf16x8*)(ksrc + q * 8);
            vv4[q] = *(const bf16x8*)(vsrc + q * 8);
        }
        __syncthreads();  // previous-iter LDS reads complete
#pragma unroll
        for (int q = 0; q < 4; ++q) {
            *(bf16x8*)(Ks + kr * 256 + ((((kseg * 4 + q) * 16)) ^ ((kr & 7) << 4))) = kv4[q];
            *(bf16x8*)(Vs + vr * 128 + ((((vh2 * 4 + q) * 16)) ^ ((vr & 7) << 4))) = vv4[q];
        }
        __syncthreads();
        // S = Q K^T  (32x64 per wave)
        f32x4 s[2][4] = {};
#pragma unroll
        for (int ks = 0; ks < 4; ++ks) {
            bf16x8 kf[4];
#pragma unroll
            for (int ni = 0; ni < 4; ++ni) {
                int row = ni * 16 + (l & 15);
                kf[ni] = *(const bf16x8*)(Ks + row * 256 +
                            ((ks * 64 + (l >> 4) * 16) ^ ((row & 7) << 4)));
            }
#pragma unroll
            for (int mi = 0; mi < 2; ++mi)
#pragma unroll
                for (int ni = 0; ni < 4; ++ni)
                    s[mi][ni] = mfma16(qf[mi][ks], kf[ni], s[mi][ni]);
        }
        // online softmax (rows spread across 16-lane groups)
#pragma unroll
        for (int mi = 0; mi < 2; ++mi)
#pragma unroll
            for (int r = 0; r < 4; ++r) {
                float sm = fmaxf(fmaxf(s[mi][0][r], s[mi][1][r]),
                                 fmaxf(s[mi][2][r], s[mi][3][r]));
                for (int o = 1; o < 16; o <<= 1) sm = fmaxf(sm, __shfl_xor(sm, o));
                float mn = fmaxf(mrun[mi][r], sm);
                float f = expf(mrun[mi][r] - mn);
                mrun[mi][r] = mn;
                float ps = 0.f;
#pragma unroll
                for (int ni = 0; ni < 4; ++ni) {
                    float p = expf(s[mi][ni][r] - mn);
                    s[mi][ni][r] = p;
                    ps += p;
                }
                for (int o = 1; o < 16; o <<= 1) ps += __shfl_xor(ps, o);
                lrun[mi][r] = lrun[mi][r] * f + ps;
#pragma unroll
                for (int nd = 0; nd < 8; ++nd) oacc[mi][nd][r] *= f;
            }
        // write P (C-layout) to wave-private LDS, swizzled
#pragma unroll
        for (int mi = 0; mi < 2; ++mi)
#pragma unroll
            for (int ni = 0; ni < 4; ++ni)
#pragma unroll
                for (int r = 0; r < 4; ++r) {
                    int qr = mi * 16 + ((l >> 4) << 2) + r;
                    int tcb = (ni * 16 + (l & 15)) * 2;
                    *(unsigned short*)(Ps + qr * 128 + (tcb ^ ((qr & 7) << 4))) =
                        f2bf(s[mi][ni][r]);
                }
        // O += P V  (read P back in A-layout; Vs rows are d, cols t)
#pragma unroll
        for (int ks = 0; ks < 2; ++ks) {
            bf16x8 pa[2];
#pragma unroll
            for (int mi = 0; mi < 2; ++mi) {
                int qr = mi * 16 + (l & 15);
                pa[mi] = *(const bf16x8*)(Ps + qr * 128 +
                            ((ks * 64 + (l >> 4) * 16) ^ ((qr & 7) << 4)));
            }
#pragma unroll
            for (int nd = 0; nd < 8; ++nd) {
                int row = nd * 16 + (l & 15);
                bf16x8 vf = *(const bf16x8*)(Vs + row * 128 +
                            ((ks * 64 + (l >> 4) * 16) ^ ((row & 7) << 4)));
#pragma unroll
                for (int mi = 0; mi < 2; ++mi)
                    oacc[mi][nd] = mfma16(pa[mi], vf, oacc[mi][nd]);
            }
        }
    }
    // epilogue: o / l * sigmoid(gate)
#pragma unroll
    for (int mi = 0; mi < 2; ++mi)
#pragma unroll
        for (int r = 0; r < 4; ++r) {
            int row = q0 + mi * 16 + ((l >> 4) << 2) + r;
            float sc = (1.f / lrun[mi][r]) * gate[(size_t)row * HQ + qh];
#pragma unroll
            for (int nd = 0; nd < 8; ++nd)
                og[(size_t)row * Q_SIZE + qh * 128 + nd * 16 + (l & 15)] =
                    f2bf(oacc[mi][nd][r] * sc);
        }
}

extern "C" void kernel_launch(void* const* d_in, const int* in_sizes, int n_in,
                              void* d_out, int out_size, void* d_ws, size_t ws_size,
                              hipStream_t stream) {
    const float* hidden = (const float*)d_in[0];
    const float* rope   = (const float*)d_in[1];
    const float* pnw    = (const float*)d_in[2];
    const float* qkvw   = (const float*)d_in[3];
    const float* qnw    = (const float*)d_in[4];
    const float* knw    = (const float*)d_in[5];
    const float* projw  = (const float*)d_in[6];
    const int*   mids   = (const int*)d_in[7];
    float* out = (float*)d_out;

    char* ws = (char*)d_ws;
    int* meta = (int*)ws;
    int* perm = (int*)(ws + 64);
    unsigned short* h   = (unsigned short*)(ws + (1 << 14));
    unsigned short* qkv = h   + (size_t)N_TOK * HIDDEN;
    unsigned short* qb  = qkv + (size_t)N_TOK * QKV_OUT;
    unsigned short* kb  = qb  + (size_t)N_TOK * Q_SIZE;
    unsigned short* vT  = kb  + (size_t)N_TOK * KV_SIZE;
    unsigned short* og  = vT  + (size_t)N_TOK * KV_SIZE;
    float* gate = (float*)(og + (size_t)N_TOK * Q_SIZE);
    size_t needed = (size_t)(gate + (size_t)N_TOK * HQ) - (size_t)ws;
    if (ws_size < needed) return;  // loud failure: output stays zero

    k_sort<<<1, 64, 0, stream>>>(mids, meta, perm);
    k_prenorm<<<2048, 256, 0, stream>>>(hidden, pnw, meta, perm, h);
    k_moe_gemm<QKV_OUT, false><<<dim3(57, 16, 3), 256, 0, stream>>>(
        h, qkvw, qkv, nullptr, meta, perm);
    k_qknorm<<<2048, 256, 0, stream>>>(qkv, rope, qnw, knw, meta, perm, qb, kb, gate);
    k_vtrans<<<dim3(32, 2, 8), 256, 0, stream>>>(qkv, vT);
    k_attn<<<dim3(16, 40), 256, 0, stream>>>(qb, kb, vT, gate, og);
    k_moe_gemm<HIDDEN, true><<<dim3(40, 16, 3), 256, 0, stream>>>(
        og, projw, nullptr, out, meta, perm);
}